// Round 14
// baseline (321.233 us; speedup 1.0000x reference)
//
#include <hip/hip_runtime.h>
#include <hip/hip_bf16.h>

#define BB 64
#define PP 100
#define NN 1000
#define EE 512
#define HH 8
#define KDD 64
#define MM 10
#define ROWS (BB*PP)          // 6400
#define K1K 1026              // 2E+2
#define INVSQE 0.044194173824159216f  // 1/sqrt(512)
#define CLIPV 10.0f

union F4 { float4 v; float f[4]; };

using bf16x8 = __attribute__((ext_vector_type(8))) short;
using bf16x4 = __attribute__((ext_vector_type(4))) unsigned short;
using f32x4  = __attribute__((ext_vector_type(4))) float;

// HW RNE convert — compiler fuses pairs into v_cvt_pk_bf16_f32; register-neutral.
__device__ inline unsigned short f2bf(float x) {
  __hip_bfloat16 h = __float2bfloat16(x);
  unsigned short u;
  __builtin_memcpy(&u, &h, sizeof(u));
  return u;
}

__device__ inline float bf2f(unsigned short s) {
  return __uint_as_float(((unsigned)s) << 16);
}

__device__ inline float fast_tanh(float x) {
  float e = __expf(2.0f * x);
  return 1.0f - 2.0f / (e + 1.0f);
}

// ---------------------------------------------------------------- K0: row max of cur_dist
__global__ __launch_bounds__(256) void k_rowmax(const float* __restrict__ cd,
                                                float* __restrict__ rmax) {
  int row = blockIdx.x * 4 + (threadIdx.x >> 6);
  int lane = threadIdx.x & 63;
  const float* src = cd + (size_t)row * NN;
  float m = -1e30f;
  for (int i = lane; i < NN; i += 64) m = fmaxf(m, src[i]);
  #pragma unroll
  for (int off = 32; off; off >>= 1) m = fmaxf(m, __shfl_xor(m, off));
  if (lane == 0) rmax[row] = m;
}

// ---------------------------------------------------------------- K1: q = q_first + heads(X @ Wq^T) + heads(info @ dis_emb^T)  (MFMA bf16)
__global__ __launch_bounds__(256) void k_qgemm(
    const float* __restrict__ eln, const float* __restrict__ ela,
    const float* __restrict__ lengths, const float* __restrict__ max_dis,
    const float* __restrict__ remain, const float* __restrict__ q_first,
    const float* __restrict__ Wq, const float* __restrict__ dis_emb,
    const int* __restrict__ depot, const int* __restrict__ route_cnt,
    const int* __restrict__ left_city, const int* __restrict__ city_num,
    float* __restrict__ qout) {
  __shared__ unsigned short Xs[64][40];
  __shared__ unsigned short Ws[64][40];
  __shared__ float info_s[64][4];
  __shared__ float fl_s[64][2];
  const int t = threadIdx.x;
  const int lane = t & 63;
  const int w = t >> 6;
  const int lr = lane & 15, lg = lane >> 4;
  const int rowBase = blockIdx.y * 64, colBase = blockIdx.x * 64;

  if (t < 64) {
    int row = rowBase + t;
    int b = row / PP;
    int rc = route_cnt[row];
    int rn = depot[b] - 1;
    info_s[t][0] = lengths[row * MM + rc];
    info_s[t][1] = lengths[row * MM + rn];
    info_s[t][2] = max_dis[row];
    info_s[t][3] = remain[row];
    fl_s[t][0] = 1.0f - (float)(rc + 1) / (float)(rn + 1);
    fl_s[t][1] = (float)left_city[row] / (float)city_num[0];
  }

  f32x4 acc[4];
  #pragma unroll
  for (int m = 0; m < 4; ++m) { acc[m][0] = 0.f; acc[m][1] = 0.f; acc[m][2] = 0.f; acc[m][3] = 0.f; }

  for (int kt = 0; kt < 32; ++kt) {
    const float* xsrc = (kt < 16) ? eln : ela;
    const int koff = (kt & 15) * 32;
    __syncthreads();
    #pragma unroll
    for (int i = 0; i < 2; ++i) {
      int s = i * 256 + t;
      int r = s >> 3, c4 = (s & 7) * 4;
      F4 xv, wv;
      xv.v = *(const float4*)&xsrc[(size_t)(rowBase + r) * 512 + koff + c4];
      wv.v = *(const float4*)&Wq[(size_t)(colBase + r) * K1K + kt * 32 + c4];
      unsigned short* xd = &Xs[r][c4];
      unsigned short* wd = &Ws[r][c4];
      xd[0] = f2bf(xv.f[0]); xd[1] = f2bf(xv.f[1]); xd[2] = f2bf(xv.f[2]); xd[3] = f2bf(xv.f[3]);
      wd[0] = f2bf(wv.f[0]); wd[1] = f2bf(wv.f[1]); wd[2] = f2bf(wv.f[2]); wd[3] = f2bf(wv.f[3]);
    }
    __syncthreads();
    bf16x8 bfr = *(bf16x8*)&Ws[w * 16 + lr][lg * 8];
    #pragma unroll
    for (int m = 0; m < 4; ++m) {
      bf16x8 af = *(bf16x8*)&Xs[m * 16 + lr][lg * 8];
      acc[m] = __builtin_amdgcn_mfma_f32_16x16x32_bf16(af, bfr, acc[m], 0, 0, 0);
    }
  }

  const int o = colBase + w * 16 + lr;
  F4 de; de.v = *(const float4*)&dis_emb[(size_t)o * 4];
  const float wq1024 = Wq[(size_t)o * K1K + 1024];
  const float wq1025 = Wq[(size_t)o * K1K + 1025];
  const int h = o >> 6, kd = o & 63;
  #pragma unroll
  for (int m = 0; m < 4; ++m) {
    #pragma unroll
    for (int j = 0; j < 4; ++j) {
      int r = m * 16 + lg * 4 + j;
      int row = rowBase + r;
      int b = row / PP, p = row % PP;
      F4 inf; inf.v = *(const float4*)&info_s[r][0];
      float v = acc[m][j]
              + inf.f[0] * de.f[0] + inf.f[1] * de.f[1]
              + inf.f[2] * de.f[2] + inf.f[3] * de.f[3]
              + fl_s[r][0] * wq1024 + fl_s[r][1] * wq1025
              + q_first[(((size_t)b * HH + h) * PP + p) * KDD + kd];
      qout[(size_t)row * 512 + o] = v;
    }
  }
}

// ---------------------------------------------------------------- K2a: masked MHA, P-split x K-split (no-max partials).
// Grid 2048: gid = X*64 + b, X = part*16 + half*8 + h -> XCD = b%8: all 32
// blocks of a batch share one XCD's L2 (mask/K/V reuse). Each block: 64 q-rows
// (wave w owns m-tile w), 8 key chunks of its partition.
// r8's split-K failure modes fixed: LDS 27.6 KB (5 blocks/CU, was 49KB->3),
// 8 chunks amortization (was 4), and NO max-tracking: no-max softmax makes
// partials exactly summable (O_total = sum O_part, L_total = sum L_part).
// r9/r12 occupancy was GRID-limited (1024 blocks = 4/CU = 50% cap); this
// supplies 8/CU, LDS caps residency at 5 (~62%).
// VGPR must stay <= 64 (r10/r11 lesson: +16 regs halves wave slots).
__global__ __launch_bounds__(256) void k_attn_part(
    const float* __restrict__ qin, const float* __restrict__ kk,
    const float* __restrict__ vv, const float* __restrict__ mask,
    unsigned short* __restrict__ pO, float* __restrict__ pl) {
  __shared__ unsigned short Kl[64][72];    // bf16 K chunk [n][d]
  __shared__ unsigned short Vt[64][72];    // bf16 V^T chunk [d][n]
  __shared__ unsigned short PMb[64][72];   // bf16: Q stage -> mask -> P

  const int t = threadIdx.x;
  const int lane = t & 63;
  const int w = t >> 6;
  const int lr = lane & 15, lg = lane >> 4;
  const int gid = blockIdx.x;
  const int b = gid & 63;
  const int X = gid >> 6;                 // 0..31
  const int h = X & 7;
  const int half = (X >> 3) & 1;
  const int part = X >> 4;                // 0..1
  const int bh = b * HH + h;
  const int p0 = half * 64;
  const int nrows = (half == 0) ? 64 : (PP - 64);   // 64 or 36
  const bool active = (w * 16 < nrows);

  // ---- stage Q (bf16, scaled 1/8); p >= PP rows zeroed
  #pragma unroll
  for (int i = 0; i < 4; ++i) {
    int idx = i * 256 + t;                 // 64 rows x 16 float4
    int r = idx >> 4, c4 = (idx & 15) * 4;
    int p = p0 + r;
    F4 qv; qv.v = make_float4(0.f, 0.f, 0.f, 0.f);
    if (p < PP) qv.v = *(const float4*)&qin[((size_t)(b * PP + p)) * 512 + h * 64 + c4];
    unsigned short* d = &PMb[r][c4];
    d[0] = f2bf(qv.f[0] * 0.125f); d[1] = f2bf(qv.f[1] * 0.125f);
    d[2] = f2bf(qv.f[2] * 0.125f); d[3] = f2bf(qv.f[3] * 0.125f);
  }
  __syncthreads();

  bf16x8 qf[2];
  qf[0] = *(bf16x8*)&PMb[w * 16 + lr][lg * 8];
  qf[1] = *(bf16x8*)&PMb[w * 16 + lr][32 + lg * 8];
  __syncthreads();   // Q frag reads done before PMb becomes mask buffer

  float Lacc[4] = {0.f, 0.f, 0.f, 0.f};
  f32x4 Oa[4];
  #pragma unroll
  for (int dt = 0; dt < 4; ++dt) { Oa[dt][0] = 0.f; Oa[dt][1] = 0.f; Oa[dt][2] = 0.f; Oa[dt][3] = 0.f; }

  for (int cc = 0; cc < 8; ++cc) {
    const int n0 = (part * 8 + cc) * 64;

    // ---- stage K row-major bf16 (coalesced)
    #pragma unroll
    for (int i = 0; i < 4; ++i) {
      int idx = i * 256 + t;
      int r = idx >> 4, c4 = (idx & 15) * 4;
      int n = n0 + r;
      F4 kv; kv.v = make_float4(0.f, 0.f, 0.f, 0.f);
      if (n < NN) kv.v = *(const float4*)&kk[(((size_t)bh * NN) + n) * 64 + c4];
      unsigned short* d = &Kl[r][c4];
      d[0] = f2bf(kv.f[0]); d[1] = f2bf(kv.f[1]); d[2] = f2bf(kv.f[2]); d[3] = f2bf(kv.f[3]);
    }
    // ---- stage V transposed bf16 (low-conflict lane roles)
    {
      int b2 = t & 15, a = t >> 4;
      F4 rowv[4];
      #pragma unroll
      for (int r = 0; r < 4; ++r) {
        int n = n0 + 4 * b2 + r;
        rowv[r].v = (n < NN) ? *(const float4*)&vv[(((size_t)bh * NN) + n) * 64 + 4 * a]
                             : make_float4(0.f, 0.f, 0.f, 0.f);
      }
      #pragma unroll
      for (int c = 0; c < 4; ++c) {
        unsigned short* dst = &Vt[4 * a + c][4 * b2];
        dst[0] = f2bf(rowv[0].f[c]); dst[1] = f2bf(rowv[1].f[c]);
        dst[2] = f2bf(rowv[2].f[c]); dst[3] = f2bf(rowv[3].f[c]);
      }
    }
    // ---- stage mask chunk bf16 into PMb (rows < nrows only; cols >= NN -> -1e30)
    #pragma unroll
    for (int i = 0; i < 4; ++i) {
      int idx = i * 256 + t;
      int r = idx >> 4, c4 = (idx & 15) * 4;
      if (r < nrows) {
        int p = p0 + r, n = n0 + c4;
        F4 mv;
        if (n + 3 < NN) {
          mv.v = *(const float4*)&mask[((size_t)(b * PP + p)) * NN + n];
        } else {
          #pragma unroll
          for (int j = 0; j < 4; ++j)
            mv.f[j] = (n + j < NN) ? mask[((size_t)(b * PP + p)) * NN + n + j] : -1e30f;
        }
        unsigned short* d = &PMb[r][c4];
        d[0] = f2bf(mv.f[0]); d[1] = f2bf(mv.f[1]); d[2] = f2bf(mv.f[2]); d[3] = f2bf(mv.f[3]);
      }
    }
    __syncthreads();

    if (active) {
      // ---- QK^T mfma
      f32x4 sa[4];
      #pragma unroll
      for (int nb = 0; nb < 4; ++nb) { sa[nb][0] = 0.f; sa[nb][1] = 0.f; sa[nb][2] = 0.f; sa[nb][3] = 0.f; }
      #pragma unroll
      for (int kb = 0; kb < 2; ++kb)
        #pragma unroll
        for (int nb = 0; nb < 4; ++nb) {
          bf16x8 kf = *(bf16x8*)&Kl[nb * 16 + lr][kb * 32 + lg * 8];
          sa[nb] = __builtin_amdgcn_mfma_f32_16x16x32_bf16(qf[kb], kf, sa[nb], 0, 0, 0);
        }
      // ---- no-max softmax: e = exp(s + mask), P -> PMb (bf16, wave-private rows)
      #pragma unroll
      for (int j = 0; j < 4; ++j) {
        int pr = w * 16 + lg * 4 + j;
        #pragma unroll
        for (int nb = 0; nb < 4; ++nb) {
          float mv = bf2f(PMb[pr][nb * 16 + lr]);
          float e = __expf(sa[nb][j] + mv);
          Lacc[j] += e;
          PMb[pr][nb * 16 + lr] = f2bf(e);
        }
      }
      // ---- PV mfma (P read directly as bf16 fragments; wave-private rows)
      #pragma unroll
      for (int kb = 0; kb < 2; ++kb) {
        bf16x8 pf = *(bf16x8*)&PMb[w * 16 + lr][kb * 32 + lg * 8];
        #pragma unroll
        for (int dt = 0; dt < 4; ++dt) {
          bf16x8 vf = *(bf16x8*)&Vt[dt * 16 + lr][kb * 32 + lg * 8];
          Oa[dt] = __builtin_amdgcn_mfma_f32_16x16x32_bf16(pf, vf, Oa[dt], 0, 0, 0);
        }
      }
    }
    __syncthreads();
  }

  // ---- epilogue: reduce L, write UNNORMALIZED partial O (bf16) + L (fp32)
  if (active) {
    #pragma unroll
    for (int j = 0; j < 4; ++j) {
      float L = Lacc[j];
      #pragma unroll
      for (int off = 1; off < 16; off <<= 1) L += __shfl_xor(L, off);
      int plocal = w * 16 + lg * 4 + j;
      int p = p0 + plocal;
      if (p < PP) {
        #pragma unroll
        for (int dt = 0; dt < 4; ++dt)
          pO[(size_t)gid * 4096 + plocal * 64 + dt * 16 + lr] = f2bf(Oa[dt][j]);
        if (lr == 0) pl[gid * 64 + plocal] = L;
      }
    }
  }
}

// ---------------------------------------------------------------- K2b: merge 2 K-partitions -> attn_out (exact: no-max partials sum)
__global__ __launch_bounds__(256) void k_attn_merge(
    const unsigned short* __restrict__ pO, const float* __restrict__ pl,
    float* __restrict__ attn_out) {
  const int rid = blockIdx.x * 4 + (threadIdx.x >> 6);   // b*800 + h*100 + p
  const int d = threadIdx.x & 63;
  const int b = rid / (HH * PP);
  const int rem = rid % (HH * PP);
  const int h = rem / PP, p = rem % PP;
  const int half = (p >= 64) ? 1 : 0;
  const int plocal = p - half * 64;
  float O = 0.f, L = 0.f;
  #pragma unroll
  for (int part = 0; part < 2; ++part) {
    int gid = ((part * 16 + half * 8 + h) << 6) | b;
    O += bf2f(pO[(size_t)gid * 4096 + plocal * 64 + d]);
    L += pl[gid * 64 + plocal];
  }
  float inv = (L > 0.f) ? 1.0f / L : 0.f;
  attn_out[((size_t)(b * PP + p)) * 512 + h * 64 + d] = O * inv;
}

// ---------------------------------------------------------------- K3: mh = attn_out @ mh_w^T + mh_b  (MFMA bf16)
__global__ __launch_bounds__(256) void k_mhgemm(
    const float* __restrict__ A, const float* __restrict__ W,
    const float* __restrict__ bias, float* __restrict__ out) {
  __shared__ unsigned short Xs[64][40];
  __shared__ unsigned short Ws[64][40];
  const int t = threadIdx.x;
  const int lane = t & 63;
  const int w = t >> 6;
  const int lr = lane & 15, lg = lane >> 4;
  const int rowBase = blockIdx.y * 64, colBase = blockIdx.x * 64;

  f32x4 acc[4];
  #pragma unroll
  for (int m = 0; m < 4; ++m) { acc[m][0] = 0.f; acc[m][1] = 0.f; acc[m][2] = 0.f; acc[m][3] = 0.f; }

  for (int kt = 0; kt < 16; ++kt) {
    const int koff = kt * 32;
    __syncthreads();
    #pragma unroll
    for (int i = 0; i < 2; ++i) {
      int s = i * 256 + t;
      int r = s >> 3, c4 = (s & 7) * 4;
      F4 xv, wv;
      xv.v = *(const float4*)&A[(size_t)(rowBase + r) * 512 + koff + c4];
      wv.v = *(const float4*)&W[(size_t)(colBase + r) * 512 + koff + c4];
      unsigned short* xd = &Xs[r][c4];
      unsigned short* wd = &Ws[r][c4];
      xd[0] = f2bf(xv.f[0]); xd[1] = f2bf(xv.f[1]); xd[2] = f2bf(xv.f[2]); xd[3] = f2bf(xv.f[3]);
      wd[0] = f2bf(wv.f[0]); wd[1] = f2bf(wv.f[1]); wd[2] = f2bf(wv.f[2]); wd[3] = f2bf(wv.f[3]);
    }
    __syncthreads();
    bf16x8 bfr = *(bf16x8*)&Ws[w * 16 + lr][lg * 8];
    #pragma unroll
    for (int m = 0; m < 4; ++m) {
      bf16x8 af = *(bf16x8*)&Xs[m * 16 + lr][lg * 8];
      acc[m] = __builtin_amdgcn_mfma_f32_16x16x32_bf16(af, bfr, acc[m], 0, 0, 0);
    }
  }

  const int o = colBase + w * 16 + lr;
  const float bv = bias[o];
  #pragma unroll
  for (int m = 0; m < 4; ++m) {
    #pragma unroll
    for (int j = 0; j < 4; ++j) {
      int row = rowBase + m * 16 + lg * 4 + j;
      out[(size_t)row * 512 + o] = acc[m][j] + bv;
    }
  }
}

// ---------------------------------------------------------------- K4a: score2 = mh @ shk (MFMA bf16) + tanh-clip epilogue
__global__ __launch_bounds__(256) void k_final_score(
    const float* __restrict__ mh, const float* __restrict__ shk,
    const float* __restrict__ cur_dist, const float* __restrict__ rmax,
    const float* __restrict__ mask, const float* __restrict__ dist_alpha,
    float* __restrict__ sc_out) {
  __shared__ unsigned short As[112][40];
  __shared__ unsigned short Bt[64][40];
  const int t = threadIdx.x;
  const int lane = t & 63;
  const int w = t >> 6;
  const int lr = lane & 15, lg = lane >> 4;
  const int n0 = blockIdx.x * 64, b = blockIdx.y;

  f32x4 acc[7];
  #pragma unroll
  for (int m = 0; m < 7; ++m) { acc[m][0] = 0.f; acc[m][1] = 0.f; acc[m][2] = 0.f; acc[m][3] = 0.f; }

  for (int kt = 0; kt < 16; ++kt) {
    const int k0 = kt * 32;
    __syncthreads();
    #pragma unroll
    for (int i = 0; i < 4; ++i) {
      int s = i * 256 + t;
      if (s < 896) {
        int r = s >> 3, c4 = (s & 7) * 4;
        F4 xv; xv.v = make_float4(0.f, 0.f, 0.f, 0.f);
        if (r < PP) xv.v = *(const float4*)&mh[(size_t)(b * PP + r) * 512 + k0 + c4];
        unsigned short* xd = &As[r][c4];
        xd[0] = f2bf(xv.f[0]); xd[1] = f2bf(xv.f[1]); xd[2] = f2bf(xv.f[2]); xd[3] = f2bf(xv.f[3]);
      }
    }
    if (t < 128) {
      int a = t & 15, kb = t >> 4;
      F4 rowv[4];
      #pragma unroll
      for (int r = 0; r < 4; ++r) {
        int k = k0 + 4 * kb + r;
        int n = n0 + 4 * a;
        rowv[r].v = (n < NN) ? *(const float4*)&shk[((size_t)b * EE + k) * NN + n]
                             : make_float4(0.f, 0.f, 0.f, 0.f);
      }
      #pragma unroll
      for (int c = 0; c < 4; ++c) {
        unsigned short* dst = &Bt[4 * a + c][4 * kb];
        dst[0] = f2bf(rowv[0].f[c]); dst[1] = f2bf(rowv[1].f[c]);
        dst[2] = f2bf(rowv[2].f[c]); dst[3] = f2bf(rowv[3].f[c]);
      }
    }
    __syncthreads();
    bf16x8 bfr = *(bf16x8*)&Bt[w * 16 + lr][lg * 8];
    #pragma unroll
    for (int m = 0; m < 7; ++m) {
      bf16x8 af = *(bf16x8*)&As[m * 16 + lr][lg * 8];
      acc[m] = __builtin_amdgcn_mfma_f32_16x16x32_bf16(af, bfr, acc[m], 0, 0, 0);
    }
  }

  const float alpha = dist_alpha[0];
  const int n = n0 + w * 16 + lr;
  if (n < NN) {
    #pragma unroll
    for (int m = 0; m < 7; ++m) {
      #pragma unroll
      for (int j = 0; j < 4; ++j) {
        int p = m * 16 + lg * 4 + j;
        if (p >= PP) continue;
        size_t rb = (size_t)(b * PP + p) * NN;
        float rmx = rmax[b * PP + p];
        float cd = cur_dist[rb + n];
        float mk = mask[rb + n];
        sc_out[rb + n] = CLIPV * fast_tanh(acc[m][j] * INVSQE - alpha * cd / rmx) + mk;
      }
    }
  }
}

// ---------------------------------------------------------------- K4b: row softmax over N
__global__ __launch_bounds__(256) void k_softmax(const float* __restrict__ sc,
                                                 float* __restrict__ out) {
  __shared__ float redm[4];
  __shared__ float redsum[4];
  const int row = blockIdx.x;
  const int t = threadIdx.x;
  const float* src = sc + (size_t)row * NN;
  float v0[4];
  float m = -1e30f;
  #pragma unroll
  for (int i = 0; i < 4; ++i) {
    int n = i * 256 + t;
    v0[i] = (n < NN) ? src[n] : -1e30f;
    m = fmaxf(m, v0[i]);
  }
  #pragma unroll
  for (int off = 32; off; off >>= 1) m = fmaxf(m, __shfl_xor(m, off));
  int wid = t >> 6, lane = t & 63;
  if (lane == 0) redm[wid] = m;
  __syncthreads();
  m = fmaxf(fmaxf(redm[0], redm[1]), fmaxf(redm[2], redm[3]));
  float e[4];
  float s = 0.f;
  #pragma unroll
  for (int i = 0; i < 4; ++i) {
    int n = i * 256 + t;
    e[i] = (n < NN) ? __expf(v0[i] - m) : 0.f;
    s += e[i];
  }
  #pragma unroll
  for (int off = 32; off; off >>= 1) s += __shfl_xor(s, off);
  if (lane == 0) redsum[wid] = s;
  __syncthreads();
  s = redsum[0] + redsum[1] + redsum[2] + redsum[3];
  float inv = 1.0f / s;
  #pragma unroll
  for (int i = 0; i < 4; ++i) {
    int n = i * 256 + t;
    if (n < NN) out[(size_t)row * NN + n] = e[i] * inv;
  }
}

// ----------------------------------------------------------------
extern "C" void kernel_launch(void* const* d_in, const int* in_sizes, int n_in,
                              void* d_out, int out_size, void* d_ws, size_t ws_size,
                              hipStream_t stream) {
  const float* eln       = (const float*)d_in[0];
  const float* ela       = (const float*)d_in[1];
  const float* cur_dist  = (const float*)d_in[2];
  const float* ninf      = (const float*)d_in[3];
  const float* lengths   = (const float*)d_in[4];
  const float* max_dis   = (const float*)d_in[5];
  const float* remain    = (const float*)d_in[6];
  const float* q_first   = (const float*)d_in[7];
  const float* kten      = (const float*)d_in[8];
  const float* vten      = (const float*)d_in[9];
  const float* shk       = (const float*)d_in[10];
  const float* Wq        = (const float*)d_in[11];
  const float* dis_emb   = (const float*)d_in[12];
  const float* mh_w      = (const float*)d_in[13];
  const float* mh_b      = (const float*)d_in[14];
  const float* dalpha    = (const float*)d_in[15];
  const int*   depot     = (const int*)d_in[16];
  const int*   route_cnt = (const int*)d_in[17];
  const int*   left_city = (const int*)d_in[18];
  const int*   city_num  = (const int*)d_in[19];
  float* out = (float*)d_out;

  float* ws      = (float*)d_ws;
  float* q_ws    = ws;                                   // 6400*512
  float* attn_ws = q_ws + (size_t)ROWS * 512;            // 6400*512
  float* mh_ws   = attn_ws + (size_t)ROWS * 512;         // 6400*512
  float* sc_ws   = mh_ws + (size_t)ROWS * 512;           // 6400*1000
  float* rmax_ws = sc_ws + (size_t)ROWS * NN;            // 6400

  // attention partials OVERLAY the (currently dead) mh_ws+sc_ws region:
  //   pO: 2048 * 64 rows * 64 d bf16 = 8,388,608 shorts = 4,194,304 float-eq
  //   pl: 2048 * 64 fp32 = 131,072 floats
  // total 4.33M <= 9.68M available. Stream order: k_attn_part -> k_attn_merge
  // (reads partials, writes attn_ws) -> k_mhgemm overwrites mh_ws.
  unsigned short* pO_ws = (unsigned short*)mh_ws;
  float* pl_ws = mh_ws + (size_t)4194304;

  k_rowmax<<<ROWS / 4, 256, 0, stream>>>(cur_dist, rmax_ws);
  k_qgemm<<<dim3(8, 100), 256, 0, stream>>>(eln, ela, lengths, max_dis, remain,
                                            q_first, Wq, dis_emb, depot, route_cnt,
                                            left_city, city_num, q_ws);
  k_attn_part<<<2048, 256, 0, stream>>>(q_ws, kten, vten, ninf, pO_ws, pl_ws);
  k_attn_merge<<<(ROWS * HH) / 4, 256, 0, stream>>>(pO_ws, pl_ws, attn_ws);
  k_mhgemm<<<dim3(8, 100), 256, 0, stream>>>(attn_ws, mh_w, mh_b, mh_ws);
  k_final_score<<<dim3(16, 64), 256, 0, stream>>>(mh_ws, shk, cur_dist, rmax_ws,
                                                  ninf, dalpha, sc_ws);
  k_softmax<<<ROWS, 256, 0, stream>>>(sc_ws, out);
}

// Round 15
// 279.555 us; speedup vs baseline: 1.1491x; 1.1491x over previous
//
#include <hip/hip_runtime.h>
#include <hip/hip_bf16.h>

#define BB 64
#define PP 100
#define NN 1000
#define EE 512
#define HH 8
#define KDD 64
#define MM 10
#define ROWS (BB*PP)          // 6400
#define K1K 1026              // 2E+2
#define INVSQE 0.044194173824159216f  // 1/sqrt(512)
#define CLIPV 10.0f

union F4 { float4 v; float f[4]; };

using bf16x8 = __attribute__((ext_vector_type(8))) short;
using f32x4  = __attribute__((ext_vector_type(4))) float;

// Bit-twiddle RNE convert. NOTE: the "HW" __float2bfloat16 variant (r11/r12)
// cost ~19us total across kernels (NaN-handling VALU ops); keep this one.
__device__ inline unsigned short f2bf(float x) {
  unsigned u = __float_as_uint(x);
  u += 0x7FFFu + ((u >> 16) & 1u);
  return (unsigned short)(u >> 16);
}

__device__ inline float bf2f(unsigned short s) {
  return __uint_as_float(((unsigned)s) << 16);
}

__device__ inline float fast_tanh(float x) {
  float e = __expf(2.0f * x);
  return 1.0f - 2.0f / (e + 1.0f);
}

// ---------------------------------------------------------------- K0: row max of cur_dist
__global__ __launch_bounds__(256) void k_rowmax(const float* __restrict__ cd,
                                                float* __restrict__ rmax) {
  int row = blockIdx.x * 4 + (threadIdx.x >> 6);
  int lane = threadIdx.x & 63;
  const float* src = cd + (size_t)row * NN;
  float m = -1e30f;
  for (int i = lane; i < NN; i += 64) m = fmaxf(m, src[i]);
  #pragma unroll
  for (int off = 32; off; off >>= 1) m = fmaxf(m, __shfl_xor(m, off));
  if (lane == 0) rmax[row] = m;
}

// ---------------------------------------------------------------- K1: q = q_first + heads(X @ Wq^T) + heads(info @ dis_emb^T)  (MFMA bf16)
// K-step 64 (r15): halves barrier count vs K-step 32, doubles MFMA per stage.
__global__ __launch_bounds__(256) void k_qgemm(
    const float* __restrict__ eln, const float* __restrict__ ela,
    const float* __restrict__ lengths, const float* __restrict__ max_dis,
    const float* __restrict__ remain, const float* __restrict__ q_first,
    const float* __restrict__ Wq, const float* __restrict__ dis_emb,
    const int* __restrict__ depot, const int* __restrict__ route_cnt,
    const int* __restrict__ left_city, const int* __restrict__ city_num,
    float* __restrict__ qout) {
  __shared__ unsigned short Xs[64][72];
  __shared__ unsigned short Ws[64][72];
  __shared__ float info_s[64][4];
  __shared__ float fl_s[64][2];
  const int t = threadIdx.x;
  const int lane = t & 63;
  const int w = t >> 6;
  const int lr = lane & 15, lg = lane >> 4;
  const int rowBase = blockIdx.y * 64, colBase = blockIdx.x * 64;

  if (t < 64) {
    int row = rowBase + t;
    int b = row / PP;
    int rc = route_cnt[row];
    int rn = depot[b] - 1;
    info_s[t][0] = lengths[row * MM + rc];
    info_s[t][1] = lengths[row * MM + rn];
    info_s[t][2] = max_dis[row];
    info_s[t][3] = remain[row];
    fl_s[t][0] = 1.0f - (float)(rc + 1) / (float)(rn + 1);
    fl_s[t][1] = (float)left_city[row] / (float)city_num[0];
  }

  f32x4 acc[4];
  #pragma unroll
  for (int m = 0; m < 4; ++m) { acc[m][0] = 0.f; acc[m][1] = 0.f; acc[m][2] = 0.f; acc[m][3] = 0.f; }

  for (int kt = 0; kt < 16; ++kt) {
    const float* xsrc = (kt < 8) ? eln : ela;
    const int koff = (kt & 7) * 64;
    __syncthreads();   // protect LDS from previous iteration's readers
    #pragma unroll
    for (int i = 0; i < 4; ++i) {
      int s = i * 256 + t;                // 64 rows x 16 f4 slots = 1024
      int r = s >> 4, c4 = (s & 15) * 4;
      F4 xv, wv;
      xv.v = *(const float4*)&xsrc[(size_t)(rowBase + r) * 512 + koff + c4];
      wv.v = *(const float4*)&Wq[(size_t)(colBase + r) * K1K + kt * 64 + c4];
      unsigned short* xd = &Xs[r][c4];
      unsigned short* wd = &Ws[r][c4];
      xd[0] = f2bf(xv.f[0]); xd[1] = f2bf(xv.f[1]); xd[2] = f2bf(xv.f[2]); xd[3] = f2bf(xv.f[3]);
      wd[0] = f2bf(wv.f[0]); wd[1] = f2bf(wv.f[1]); wd[2] = f2bf(wv.f[2]); wd[3] = f2bf(wv.f[3]);
    }
    __syncthreads();
    #pragma unroll
    for (int kb = 0; kb < 2; ++kb) {
      bf16x8 bfr = *(bf16x8*)&Ws[w * 16 + lr][kb * 32 + lg * 8];
      #pragma unroll
      for (int m = 0; m < 4; ++m) {
        bf16x8 af = *(bf16x8*)&Xs[m * 16 + lr][kb * 32 + lg * 8];
        acc[m] = __builtin_amdgcn_mfma_f32_16x16x32_bf16(af, bfr, acc[m], 0, 0, 0);
      }
    }
  }

  const int o = colBase + w * 16 + lr;
  F4 de; de.v = *(const float4*)&dis_emb[(size_t)o * 4];
  const float wq1024 = Wq[(size_t)o * K1K + 1024];
  const float wq1025 = Wq[(size_t)o * K1K + 1025];
  const int h = o >> 6, kd = o & 63;
  #pragma unroll
  for (int m = 0; m < 4; ++m) {
    #pragma unroll
    for (int j = 0; j < 4; ++j) {
      int r = m * 16 + lg * 4 + j;
      int row = rowBase + r;
      int b = row / PP, p = row % PP;
      F4 inf; inf.v = *(const float4*)&info_s[r][0];
      float v = acc[m][j]
              + inf.f[0] * de.f[0] + inf.f[1] * de.f[1]
              + inf.f[2] * de.f[2] + inf.f[3] * de.f[3]
              + fl_s[r][0] * wq1024 + fl_s[r][1] * wq1025
              + q_first[(((size_t)b * HH + h) * PP + p) * KDD + kd];
      qout[(size_t)row * 512 + o] = v;
    }
  }
}

// ---------------------------------------------------------------- K2: masked MHA, P-split (round-9 proven config, verbatim).
// LESSONS: VGPR must stay ~64 (r10/r11: +16 regs halves wave slots, slower
// despite "better" pipelining); mask stays in LDS (r10 direct-global doubled
// FETCH); 256-thread blocks beat 512 (r13); split-K not worth the merge (r8,
// r14); occupancy plateaus ~44% regardless of grid (r14) — latency-bound.
__global__ __launch_bounds__(256) void k_attn(
    const float* __restrict__ qin, const float* __restrict__ kk,
    const float* __restrict__ vv, const float* __restrict__ mask,
    float* __restrict__ attn_out) {
  __shared__ unsigned short Kl[64][72];    // bf16 K chunk [n][d]
  __shared__ unsigned short Vt[64][72];    // bf16 V^T chunk [d][n]
  __shared__ unsigned short PMb[64][72];   // bf16: Q stage -> mask -> P

  const int t = threadIdx.x;
  const int lane = t & 63;
  const int w = t >> 6;
  const int lr = lane & 15, lg = lane >> 4;
  const int gid = blockIdx.x;
  const int b = gid & 63;
  const int X = gid >> 6;                 // 0..15
  const int h = X & 7, half = X >> 3;
  const int bh = b * HH + h;
  const int p0 = half * 64;
  const int nrows = (half == 0) ? 64 : (PP - 64);   // 64 or 36
  const bool active = (w * 16 < nrows);

  // ---- stage Q (bf16, scaled 1/8); p >= PP rows zeroed
  #pragma unroll
  for (int i = 0; i < 4; ++i) {
    int idx = i * 256 + t;                 // 64 rows x 16 float4
    int r = idx >> 4, c4 = (idx & 15) * 4;
    int p = p0 + r;
    F4 qv; qv.v = make_float4(0.f, 0.f, 0.f, 0.f);
    if (p < PP) qv.v = *(const float4*)&qin[((size_t)(b * PP + p)) * 512 + h * 64 + c4];
    unsigned short* d = &PMb[r][c4];
    d[0] = f2bf(qv.f[0] * 0.125f); d[1] = f2bf(qv.f[1] * 0.125f);
    d[2] = f2bf(qv.f[2] * 0.125f); d[3] = f2bf(qv.f[3] * 0.125f);
  }
  __syncthreads();

  bf16x8 qf[2];
  qf[0] = *(bf16x8*)&PMb[w * 16 + lr][lg * 8];
  qf[1] = *(bf16x8*)&PMb[w * 16 + lr][32 + lg * 8];
  __syncthreads();   // Q frag reads done before PMb becomes mask buffer

  float Lacc[4] = {0.f, 0.f, 0.f, 0.f};
  f32x4 Oa[4];
  #pragma unroll
  for (int dt = 0; dt < 4; ++dt) { Oa[dt][0] = 0.f; Oa[dt][1] = 0.f; Oa[dt][2] = 0.f; Oa[dt][3] = 0.f; }

  for (int ch = 0; ch < 16; ++ch) {
    const int n0 = ch * 64;

    // ---- stage K row-major bf16 (coalesced)
    #pragma unroll
    for (int i = 0; i < 4; ++i) {
      int idx = i * 256 + t;
      int r = idx >> 4, c4 = (idx & 15) * 4;
      int n = n0 + r;
      F4 kv; kv.v = make_float4(0.f, 0.f, 0.f, 0.f);
      if (n < NN) kv.v = *(const float4*)&kk[(((size_t)bh * NN) + n) * 64 + c4];
      unsigned short* d = &Kl[r][c4];
      d[0] = f2bf(kv.f[0]); d[1] = f2bf(kv.f[1]); d[2] = f2bf(kv.f[2]); d[3] = f2bf(kv.f[3]);
    }
    // ---- stage V transposed bf16 (low-conflict lane roles)
    {
      int b2 = t & 15, a = t >> 4;
      F4 rowv[4];
      #pragma unroll
      for (int r = 0; r < 4; ++r) {
        int n = n0 + 4 * b2 + r;
        rowv[r].v = (n < NN) ? *(const float4*)&vv[(((size_t)bh * NN) + n) * 64 + 4 * a]
                             : make_float4(0.f, 0.f, 0.f, 0.f);
      }
      #pragma unroll
      for (int c = 0; c < 4; ++c) {
        unsigned short* dst = &Vt[4 * a + c][4 * b2];
        dst[0] = f2bf(rowv[0].f[c]); dst[1] = f2bf(rowv[1].f[c]);
        dst[2] = f2bf(rowv[2].f[c]); dst[3] = f2bf(rowv[3].f[c]);
      }
    }
    // ---- stage mask chunk bf16 into PMb (rows < nrows only; cols >= NN -> -1e30)
    #pragma unroll
    for (int i = 0; i < 4; ++i) {
      int idx = i * 256 + t;
      int r = idx >> 4, c4 = (idx & 15) * 4;
      if (r < nrows) {
        int p = p0 + r, n = n0 + c4;
        F4 mv;
        if (n + 3 < NN) {
          mv.v = *(const float4*)&mask[((size_t)(b * PP + p)) * NN + n];
        } else {
          #pragma unroll
          for (int j = 0; j < 4; ++j)
            mv.f[j] = (n + j < NN) ? mask[((size_t)(b * PP + p)) * NN + n + j] : -1e30f;
        }
        unsigned short* d = &PMb[r][c4];
        d[0] = f2bf(mv.f[0]); d[1] = f2bf(mv.f[1]); d[2] = f2bf(mv.f[2]); d[3] = f2bf(mv.f[3]);
      }
    }
    __syncthreads();

    if (active) {
      // ---- QK^T mfma
      f32x4 sa[4];
      #pragma unroll
      for (int nb = 0; nb < 4; ++nb) { sa[nb][0] = 0.f; sa[nb][1] = 0.f; sa[nb][2] = 0.f; sa[nb][3] = 0.f; }
      #pragma unroll
      for (int kb = 0; kb < 2; ++kb)
        #pragma unroll
        for (int nb = 0; nb < 4; ++nb) {
          bf16x8 kf = *(bf16x8*)&Kl[nb * 16 + lr][kb * 32 + lg * 8];
          sa[nb] = __builtin_amdgcn_mfma_f32_16x16x32_bf16(qf[kb], kf, sa[nb], 0, 0, 0);
        }
      // ---- no-max softmax: e = exp(s + mask), P -> PMb (bf16, wave-private rows)
      #pragma unroll
      for (int j = 0; j < 4; ++j) {
        int pr = w * 16 + lg * 4 + j;
        #pragma unroll
        for (int nb = 0; nb < 4; ++nb) {
          float mv = bf2f(PMb[pr][nb * 16 + lr]);
          float e = __expf(sa[nb][j] + mv);
          Lacc[j] += e;
          PMb[pr][nb * 16 + lr] = f2bf(e);
        }
      }
      // ---- PV mfma (P read directly as bf16 fragments; wave-private rows)
      #pragma unroll
      for (int kb = 0; kb < 2; ++kb) {
        bf16x8 pf = *(bf16x8*)&PMb[w * 16 + lr][kb * 32 + lg * 8];
        #pragma unroll
        for (int dt = 0; dt < 4; ++dt) {
          bf16x8 vf = *(bf16x8*)&Vt[dt * 16 + lr][kb * 32 + lg * 8];
          Oa[dt] = __builtin_amdgcn_mfma_f32_16x16x32_bf16(pf, vf, Oa[dt], 0, 0, 0);
        }
      }
    }
    __syncthreads();
  }

  // ---- epilogue: reduce L over the 16-lane row group, normalize, write
  if (active) {
    #pragma unroll
    for (int j = 0; j < 4; ++j) {
      float L = Lacc[j];
      #pragma unroll
      for (int off = 1; off < 16; off <<= 1) L += __shfl_xor(L, off);
      int p = p0 + w * 16 + lg * 4 + j;
      if (p < PP) {
        float inv = (L > 0.f) ? 1.0f / L : 0.f;
        #pragma unroll
        for (int dt = 0; dt < 4; ++dt)
          attn_out[((size_t)(b * PP + p)) * 512 + h * 64 + dt * 16 + lr] = Oa[dt][j] * inv;
      }
    }
  }
}

// ---------------------------------------------------------------- K3: mh = attn_out @ mh_w^T + mh_b  (MFMA bf16, K-step 64)
__global__ __launch_bounds__(256) void k_mhgemm(
    const float* __restrict__ A, const float* __restrict__ W,
    const float* __restrict__ bias, float* __restrict__ out) {
  __shared__ unsigned short Xs[64][72];
  __shared__ unsigned short Ws[64][72];
  const int t = threadIdx.x;
  const int lane = t & 63;
  const int w = t >> 6;
  const int lr = lane & 15, lg = lane >> 4;
  const int rowBase = blockIdx.y * 64, colBase = blockIdx.x * 64;

  f32x4 acc[4];
  #pragma unroll
  for (int m = 0; m < 4; ++m) { acc[m][0] = 0.f; acc[m][1] = 0.f; acc[m][2] = 0.f; acc[m][3] = 0.f; }

  for (int kt = 0; kt < 8; ++kt) {
    const int koff = kt * 64;
    __syncthreads();
    #pragma unroll
    for (int i = 0; i < 4; ++i) {
      int s = i * 256 + t;                // 64 x 16 f4 slots
      int r = s >> 4, c4 = (s & 15) * 4;
      F4 xv, wv;
      xv.v = *(const float4*)&A[(size_t)(rowBase + r) * 512 + koff + c4];
      wv.v = *(const float4*)&W[(size_t)(colBase + r) * 512 + koff + c4];
      unsigned short* xd = &Xs[r][c4];
      unsigned short* wd = &Ws[r][c4];
      xd[0] = f2bf(xv.f[0]); xd[1] = f2bf(xv.f[1]); xd[2] = f2bf(xv.f[2]); xd[3] = f2bf(xv.f[3]);
      wd[0] = f2bf(wv.f[0]); wd[1] = f2bf(wv.f[1]); wd[2] = f2bf(wv.f[2]); wd[3] = f2bf(wv.f[3]);
    }
    __syncthreads();
    #pragma unroll
    for (int kb = 0; kb < 2; ++kb) {
      bf16x8 bfr = *(bf16x8*)&Ws[w * 16 + lr][kb * 32 + lg * 8];
      #pragma unroll
      for (int m = 0; m < 4; ++m) {
        bf16x8 af = *(bf16x8*)&Xs[m * 16 + lr][kb * 32 + lg * 8];
        acc[m] = __builtin_amdgcn_mfma_f32_16x16x32_bf16(af, bfr, acc[m], 0, 0, 0);
      }
    }
  }

  const int o = colBase + w * 16 + lr;
  const float bv = bias[o];
  #pragma unroll
  for (int m = 0; m < 4; ++m) {
    #pragma unroll
    for (int j = 0; j < 4; ++j) {
      int row = rowBase + m * 16 + lg * 4 + j;
      out[(size_t)row * 512 + o] = acc[m][j] + bv;
    }
  }
}

// ---------------------------------------------------------------- K4a: score2 = mh @ shk (MFMA bf16, K-step 64) + tanh-clip epilogue
__global__ __launch_bounds__(256) void k_final_score(
    const float* __restrict__ mh, const float* __restrict__ shk,
    const float* __restrict__ cur_dist, const float* __restrict__ rmax,
    const float* __restrict__ mask, const float* __restrict__ dist_alpha,
    float* __restrict__ sc_out) {
  __shared__ unsigned short As[112][72];
  __shared__ unsigned short Bt[64][72];
  const int t = threadIdx.x;
  const int lane = t & 63;
  const int w = t >> 6;
  const int lr = lane & 15, lg = lane >> 4;
  const int n0 = blockIdx.x * 64, b = blockIdx.y;

  f32x4 acc[7];
  #pragma unroll
  for (int m = 0; m < 7; ++m) { acc[m][0] = 0.f; acc[m][1] = 0.f; acc[m][2] = 0.f; acc[m][3] = 0.f; }

  for (int kt = 0; kt < 8; ++kt) {
    const int k0 = kt * 64;
    __syncthreads();
    // stage A chunk [112][64] (pad rows >= 100 with 0): 1792 f4 slots
    #pragma unroll
    for (int i = 0; i < 7; ++i) {
      int s = i * 256 + t;
      if (s < 1792) {
        int r = s >> 4, c4 = (s & 15) * 4;
        F4 xv; xv.v = make_float4(0.f, 0.f, 0.f, 0.f);
        if (r < PP) xv.v = *(const float4*)&mh[(size_t)(b * PP + r) * 512 + k0 + c4];
        unsigned short* xd = &As[r][c4];
        xd[0] = f2bf(xv.f[0]); xd[1] = f2bf(xv.f[1]); xd[2] = f2bf(xv.f[2]); xd[3] = f2bf(xv.f[3]);
      }
    }
    // stage B transposed: Bt[n - n0][k - k0], 64x64 from shk[b][k][n]
    {
      int a = t & 15, kb = t >> 4;        // a: n-group, kb: k-group (0..15)
      F4 rowv[4];
      #pragma unroll
      for (int r = 0; r < 4; ++r) {
        int k = k0 + 4 * kb + r;
        int n = n0 + 4 * a;
        rowv[r].v = (n < NN) ? *(const float4*)&shk[((size_t)b * EE + k) * NN + n]
                             : make_float4(0.f, 0.f, 0.f, 0.f);
      }
      #pragma unroll
      for (int c = 0; c < 4; ++c) {
        unsigned short* dst = &Bt[4 * a + c][4 * kb];
        dst[0] = f2bf(rowv[0].f[c]); dst[1] = f2bf(rowv[1].f[c]);
        dst[2] = f2bf(rowv[2].f[c]); dst[3] = f2bf(rowv[3].f[c]);
      }
    }
    __syncthreads();
    #pragma unroll
    for (int kb = 0; kb < 2; ++kb) {
      bf16x8 bfr = *(bf16x8*)&Bt[w * 16 + lr][kb * 32 + lg * 8];
      #pragma unroll
      for (int m = 0; m < 7; ++m) {
        bf16x8 af = *(bf16x8*)&As[m * 16 + lr][kb * 32 + lg * 8];
        acc[m] = __builtin_amdgcn_mfma_f32_16x16x32_bf16(af, bfr, acc[m], 0, 0, 0);
      }
    }
  }

  const float alpha = dist_alpha[0];
  const int n = n0 + w * 16 + lr;
  if (n < NN) {
    #pragma unroll
    for (int m = 0; m < 7; ++m) {
      #pragma unroll
      for (int j = 0; j < 4; ++j) {
        int p = m * 16 + lg * 4 + j;
        if (p >= PP) continue;
        size_t rb = (size_t)(b * PP + p) * NN;
        float rmx = rmax[b * PP + p];
        float cd = cur_dist[rb + n];
        float mk = mask[rb + n];
        sc_out[rb + n] = CLIPV * fast_tanh(acc[m][j] * INVSQE - alpha * cd / rmx) + mk;
      }
    }
  }
}

// ---------------------------------------------------------------- K4b: row softmax over N — NO-MAX variant.
// sc values are 10*tanh(.) + mask: bounded by +-10 (mask 0) or ~-1e30
// (masked -> exp underflows to 0). exp(s) <= 2.2e4, row sum <= 2.2e7: exact
// in fp32 without max subtraction -> one reduce pass instead of two.
__global__ __launch_bounds__(256) void k_softmax(const float* __restrict__ sc,
                                                 float* __restrict__ out) {
  __shared__ float redsum[4];
  const int row = blockIdx.x;
  const int t = threadIdx.x;
  const float* src = sc + (size_t)row * NN;
  float e[4];
  float s = 0.f;
  #pragma unroll
  for (int i = 0; i < 4; ++i) {
    int n = i * 256 + t;
    e[i] = (n < NN) ? __expf(src[n]) : 0.f;
    s += e[i];
  }
  #pragma unroll
  for (int off = 32; off; off >>= 1) s += __shfl_xor(s, off);
  int wid = t >> 6, lane = t & 63;
  if (lane == 0) redsum[wid] = s;
  __syncthreads();
  s = redsum[0] + redsum[1] + redsum[2] + redsum[3];
  float inv = 1.0f / s;
  #pragma unroll
  for (int i = 0; i < 4; ++i) {
    int n = i * 256 + t;
    if (n < NN) out[(size_t)row * NN + n] = e[i] * inv;
  }
}

// ----------------------------------------------------------------
extern "C" void kernel_launch(void* const* d_in, const int* in_sizes, int n_in,
                              void* d_out, int out_size, void* d_ws, size_t ws_size,
                              hipStream_t stream) {
  const float* eln       = (const float*)d_in[0];
  const float* ela       = (const float*)d_in[1];
  const float* cur_dist  = (const float*)d_in[2];
  const float* ninf      = (const float*)d_in[3];
  const float* lengths   = (const float*)d_in[4];
  const float* max_dis   = (const float*)d_in[5];
  const float* remain    = (const float*)d_in[6];
  const float* q_first   = (const float*)d_in[7];
  const float* kten      = (const float*)d_in[8];
  const float* vten      = (const float*)d_in[9];
  const float* shk       = (const float*)d_in[10];
  const float* Wq        = (const float*)d_in[11];
  const float* dis_emb   = (const float*)d_in[12];
  const float* mh_w      = (const float*)d_in[13];
  const float* mh_b      = (const float*)d_in[14];
  const float* dalpha    = (const float*)d_in[15];
  const int*   depot     = (const int*)d_in[16];
  const int*   route_cnt = (const int*)d_in[17];
  const int*   left_city = (const int*)d_in[18];
  const int*   city_num  = (const int*)d_in[19];
  float* out = (float*)d_out;

  float* ws      = (float*)d_ws;
  float* q_ws    = ws;                                   // 6400*512
  float* attn_ws = q_ws + (size_t)ROWS * 512;            // 6400*512
  float* mh_ws   = attn_ws + (size_t)ROWS * 512;         // 6400*512
  float* sc_ws   = mh_ws + (size_t)ROWS * 512;           // 6400*1000
  float* rmax_ws = sc_ws + (size_t)ROWS * NN;            // 6400

  k_rowmax<<<ROWS / 4, 256, 0, stream>>>(cur_dist, rmax_ws);
  k_qgemm<<<dim3(8, 100), 256, 0, stream>>>(eln, ela, lengths, max_dis, remain,
                                            q_first, Wq, dis_emb, depot, route_cnt,
                                            left_city, city_num, q_ws);
  k_attn<<<1024, 256, 0, stream>>>(q_ws, kten, vten, ninf, attn_ws);
  k_mhgemm<<<dim3(8, 100), 256, 0, stream>>>(attn_ws, mh_w, mh_b, mh_ws);
  k_final_score<<<dim3(16, 64), 256, 0, stream>>>(mh_ws, shk, cur_dist, rmax_ws,
                                                  ninf, dalpha, sc_ws);
  k_softmax<<<ROWS, 256, 0, stream>>>(sc_ws, out);
}

// Round 16
// 264.118 us; speedup vs baseline: 1.2162x; 1.0584x over previous
//
#include <hip/hip_runtime.h>
#include <hip/hip_bf16.h>

#define BB 64
#define PP 100
#define NN 1000
#define EE 512
#define HH 8
#define KDD 64
#define MM 10
#define ROWS (BB*PP)          // 6400
#define K1K 1026              // 2E+2
#define INVSQE 0.044194173824159216f  // 1/sqrt(512)
#define CLIPV 10.0f

union F4 { float4 v; float f[4]; };

using bf16x8 = __attribute__((ext_vector_type(8))) short;
using f32x4  = __attribute__((ext_vector_type(4))) float;

// Bit-twiddle RNE convert (HW __float2bfloat16 variant cost ~19us total, r12).
__device__ inline unsigned short f2bf(float x) {
  unsigned u = __float_as_uint(x);
  u += 0x7FFFu + ((u >> 16) & 1u);
  return (unsigned short)(u >> 16);
}

__device__ inline float bf2f(unsigned short s) {
  return __uint_as_float(((unsigned)s) << 16);
}

__device__ inline float fast_tanh(float x) {
  float e = __expf(2.0f * x);
  return 1.0f - 2.0f / (e + 1.0f);
}

__device__ inline bf16x8 bf8_zero() {
  bf16x8 v;
  #pragma unroll
  for (int i = 0; i < 8; ++i) v[i] = 0;
  return v;
}

// ---------------------------------------------------------------- K0: row max of cur_dist
__global__ __launch_bounds__(256) void k_rowmax(const float* __restrict__ cd,
                                                float* __restrict__ rmax) {
  int row = blockIdx.x * 4 + (threadIdx.x >> 6);
  int lane = threadIdx.x & 63;
  const float* src = cd + (size_t)row * NN;
  float m = -1e30f;
  for (int i = lane; i < NN; i += 64) m = fmaxf(m, src[i]);
  #pragma unroll
  for (int off = 32; off; off >>= 1) m = fmaxf(m, __shfl_xor(m, off));
  if (lane == 0) rmax[row] = m;
}

// ---------------------------------------------------------------- K1: q = q_first + heads(X @ Wq^T) + heads(info @ dis_emb^T)
// MFMA bf16, K-step 64. OUTPUT IS bf16 (consumer k_attn converted anyway —
// identical rounding, half the traffic).
__global__ __launch_bounds__(256) void k_qgemm(
    const float* __restrict__ eln, const float* __restrict__ ela,
    const float* __restrict__ lengths, const float* __restrict__ max_dis,
    const float* __restrict__ remain, const float* __restrict__ q_first,
    const float* __restrict__ Wq, const float* __restrict__ dis_emb,
    const int* __restrict__ depot, const int* __restrict__ route_cnt,
    const int* __restrict__ left_city, const int* __restrict__ city_num,
    unsigned short* __restrict__ qout) {
  __shared__ unsigned short Xs[64][72];
  __shared__ unsigned short Ws[64][72];
  __shared__ float info_s[64][4];
  __shared__ float fl_s[64][2];
  const int t = threadIdx.x;
  const int lane = t & 63;
  const int w = t >> 6;
  const int lr = lane & 15, lg = lane >> 4;
  const int rowBase = blockIdx.y * 64, colBase = blockIdx.x * 64;

  if (t < 64) {
    int row = rowBase + t;
    int b = row / PP;
    int rc = route_cnt[row];
    int rn = depot[b] - 1;
    info_s[t][0] = lengths[row * MM + rc];
    info_s[t][1] = lengths[row * MM + rn];
    info_s[t][2] = max_dis[row];
    info_s[t][3] = remain[row];
    fl_s[t][0] = 1.0f - (float)(rc + 1) / (float)(rn + 1);
    fl_s[t][1] = (float)left_city[row] / (float)city_num[0];
  }

  f32x4 acc[4];
  #pragma unroll
  for (int m = 0; m < 4; ++m) { acc[m][0] = 0.f; acc[m][1] = 0.f; acc[m][2] = 0.f; acc[m][3] = 0.f; }

  for (int kt = 0; kt < 16; ++kt) {
    const float* xsrc = (kt < 8) ? eln : ela;
    const int koff = (kt & 7) * 64;
    __syncthreads();
    #pragma unroll
    for (int i = 0; i < 4; ++i) {
      int s = i * 256 + t;                // 64 rows x 16 f4 slots = 1024
      int r = s >> 4, c4 = (s & 15) * 4;
      F4 xv, wv;
      xv.v = *(const float4*)&xsrc[(size_t)(rowBase + r) * 512 + koff + c4];
      wv.v = *(const float4*)&Wq[(size_t)(colBase + r) * K1K + kt * 64 + c4];
      unsigned short* xd = &Xs[r][c4];
      unsigned short* wd = &Ws[r][c4];
      xd[0] = f2bf(xv.f[0]); xd[1] = f2bf(xv.f[1]); xd[2] = f2bf(xv.f[2]); xd[3] = f2bf(xv.f[3]);
      wd[0] = f2bf(wv.f[0]); wd[1] = f2bf(wv.f[1]); wd[2] = f2bf(wv.f[2]); wd[3] = f2bf(wv.f[3]);
    }
    __syncthreads();
    #pragma unroll
    for (int kb = 0; kb < 2; ++kb) {
      bf16x8 bfr = *(bf16x8*)&Ws[w * 16 + lr][kb * 32 + lg * 8];
      #pragma unroll
      for (int m = 0; m < 4; ++m) {
        bf16x8 af = *(bf16x8*)&Xs[m * 16 + lr][kb * 32 + lg * 8];
        acc[m] = __builtin_amdgcn_mfma_f32_16x16x32_bf16(af, bfr, acc[m], 0, 0, 0);
      }
    }
  }

  const int o = colBase + w * 16 + lr;
  F4 de; de.v = *(const float4*)&dis_emb[(size_t)o * 4];
  const float wq1024 = Wq[(size_t)o * K1K + 1024];
  const float wq1025 = Wq[(size_t)o * K1K + 1025];
  const int h = o >> 6, kd = o & 63;
  #pragma unroll
  for (int m = 0; m < 4; ++m) {
    #pragma unroll
    for (int j = 0; j < 4; ++j) {
      int r = m * 16 + lg * 4 + j;
      int row = rowBase + r;
      int b = row / PP, p = row % PP;
      F4 inf; inf.v = *(const float4*)&info_s[r][0];
      float v = acc[m][j]
              + inf.f[0] * de.f[0] + inf.f[1] * de.f[1]
              + inf.f[2] * de.f[2] + inf.f[3] * de.f[3]
              + fl_s[r][0] * wq1024 + fl_s[r][1] * wq1025
              + q_first[(((size_t)b * HH + h) * PP + p) * KDD + kd];
      qout[(size_t)row * 512 + o] = f2bf(v);
    }
  }
}

// ---------------------------------------------------------------- K2: masked MHA, P-split (r9/r15 proven schedule; bf16 I/O).
// LESSONS: VGPR ~64 (r10/r11: more regs = fewer wave slots = slower); mask in
// LDS (r10); 256-thread blocks (r13); no split-K (r8/r14); plateau ~150us.
// r16: Q arrives bf16 (pure 16B copies, no scale — 1/8 folded into softmax as
// exact fmaf); O written bf16 (consumer converted anyway). K/V/mask staging
// and the chunk schedule are UNCHANGED.
__global__ __launch_bounds__(256) void k_attn(
    const unsigned short* __restrict__ qin, const float* __restrict__ kk,
    const float* __restrict__ vv, const float* __restrict__ mask,
    unsigned short* __restrict__ attn_out) {
  __shared__ unsigned short Kl[64][72];    // bf16 K chunk [n][d]
  __shared__ unsigned short Vt[64][72];    // bf16 V^T chunk [d][n]
  __shared__ unsigned short PMb[64][72];   // bf16: Q stage -> mask -> P

  const int t = threadIdx.x;
  const int lane = t & 63;
  const int w = t >> 6;
  const int lr = lane & 15, lg = lane >> 4;
  const int gid = blockIdx.x;
  const int b = gid & 63;
  const int X = gid >> 6;                 // 0..15
  const int h = X & 7, half = X >> 3;
  const int bh = b * HH + h;
  const int p0 = half * 64;
  const int nrows = (half == 0) ? 64 : (PP - 64);   // 64 or 36
  const bool active = (w * 16 < nrows);

  // ---- stage Q (bf16 copy, unscaled); p >= PP rows zeroed
  #pragma unroll
  for (int i = 0; i < 2; ++i) {
    int idx = i * 256 + t;                 // 64 rows x 8 ushort8 slots = 512
    int r = idx >> 3, c8 = (idx & 7) * 8;
    int p = p0 + r;
    bf16x8 qv = bf8_zero();
    if (p < PP) qv = *(const bf16x8*)&qin[((size_t)(b * PP + p)) * 512 + h * 64 + c8];
    *(bf16x8*)&PMb[r][c8] = qv;
  }
  __syncthreads();

  bf16x8 qf[2];
  qf[0] = *(bf16x8*)&PMb[w * 16 + lr][lg * 8];
  qf[1] = *(bf16x8*)&PMb[w * 16 + lr][32 + lg * 8];
  __syncthreads();   // Q frag reads done before PMb becomes mask buffer

  float Lacc[4] = {0.f, 0.f, 0.f, 0.f};
  f32x4 Oa[4];
  #pragma unroll
  for (int dt = 0; dt < 4; ++dt) { Oa[dt][0] = 0.f; Oa[dt][1] = 0.f; Oa[dt][2] = 0.f; Oa[dt][3] = 0.f; }

  for (int ch = 0; ch < 16; ++ch) {
    const int n0 = ch * 64;

    // ---- stage K row-major bf16 (coalesced)
    #pragma unroll
    for (int i = 0; i < 4; ++i) {
      int idx = i * 256 + t;
      int r = idx >> 4, c4 = (idx & 15) * 4;
      int n = n0 + r;
      F4 kv; kv.v = make_float4(0.f, 0.f, 0.f, 0.f);
      if (n < NN) kv.v = *(const float4*)&kk[(((size_t)bh * NN) + n) * 64 + c4];
      unsigned short* d = &Kl[r][c4];
      d[0] = f2bf(kv.f[0]); d[1] = f2bf(kv.f[1]); d[2] = f2bf(kv.f[2]); d[3] = f2bf(kv.f[3]);
    }
    // ---- stage V transposed bf16 (low-conflict lane roles)
    {
      int b2 = t & 15, a = t >> 4;
      F4 rowv[4];
      #pragma unroll
      for (int r = 0; r < 4; ++r) {
        int n = n0 + 4 * b2 + r;
        rowv[r].v = (n < NN) ? *(const float4*)&vv[(((size_t)bh * NN) + n) * 64 + 4 * a]
                             : make_float4(0.f, 0.f, 0.f, 0.f);
      }
      #pragma unroll
      for (int c = 0; c < 4; ++c) {
        unsigned short* dst = &Vt[4 * a + c][4 * b2];
        dst[0] = f2bf(rowv[0].f[c]); dst[1] = f2bf(rowv[1].f[c]);
        dst[2] = f2bf(rowv[2].f[c]); dst[3] = f2bf(rowv[3].f[c]);
      }
    }
    // ---- stage mask chunk bf16 into PMb (rows < nrows only; cols >= NN -> -1e30)
    #pragma unroll
    for (int i = 0; i < 4; ++i) {
      int idx = i * 256 + t;
      int r = idx >> 4, c4 = (idx & 15) * 4;
      if (r < nrows) {
        int p = p0 + r, n = n0 + c4;
        F4 mv;
        if (n + 3 < NN) {
          mv.v = *(const float4*)&mask[((size_t)(b * PP + p)) * NN + n];
        } else {
          #pragma unroll
          for (int j = 0; j < 4; ++j)
            mv.f[j] = (n + j < NN) ? mask[((size_t)(b * PP + p)) * NN + n + j] : -1e30f;
        }
        unsigned short* d = &PMb[r][c4];
        d[0] = f2bf(mv.f[0]); d[1] = f2bf(mv.f[1]); d[2] = f2bf(mv.f[2]); d[3] = f2bf(mv.f[3]);
      }
    }
    __syncthreads();

    if (active) {
      // ---- QK^T mfma (unscaled q; 1/8 applied below, exact)
      f32x4 sa[4];
      #pragma unroll
      for (int nb = 0; nb < 4; ++nb) { sa[nb][0] = 0.f; sa[nb][1] = 0.f; sa[nb][2] = 0.f; sa[nb][3] = 0.f; }
      #pragma unroll
      for (int kb = 0; kb < 2; ++kb)
        #pragma unroll
        for (int nb = 0; nb < 4; ++nb) {
          bf16x8 kf = *(bf16x8*)&Kl[nb * 16 + lr][kb * 32 + lg * 8];
          sa[nb] = __builtin_amdgcn_mfma_f32_16x16x32_bf16(qf[kb], kf, sa[nb], 0, 0, 0);
        }
      // ---- no-max softmax: e = exp(s/8 + mask), P -> PMb (bf16, wave-private)
      #pragma unroll
      for (int j = 0; j < 4; ++j) {
        int pr = w * 16 + lg * 4 + j;
        #pragma unroll
        for (int nb = 0; nb < 4; ++nb) {
          float mv = bf2f(PMb[pr][nb * 16 + lr]);
          float e = __expf(fmaf(sa[nb][j], 0.125f, mv));
          Lacc[j] += e;
          PMb[pr][nb * 16 + lr] = f2bf(e);
        }
      }
      // ---- PV mfma
      #pragma unroll
      for (int kb = 0; kb < 2; ++kb) {
        bf16x8 pf = *(bf16x8*)&PMb[w * 16 + lr][kb * 32 + lg * 8];
        #pragma unroll
        for (int dt = 0; dt < 4; ++dt) {
          bf16x8 vf = *(bf16x8*)&Vt[dt * 16 + lr][kb * 32 + lg * 8];
          Oa[dt] = __builtin_amdgcn_mfma_f32_16x16x32_bf16(pf, vf, Oa[dt], 0, 0, 0);
        }
      }
    }
    __syncthreads();
  }

  // ---- epilogue: reduce L, normalize, write bf16
  if (active) {
    #pragma unroll
    for (int j = 0; j < 4; ++j) {
      float L = Lacc[j];
      #pragma unroll
      for (int off = 1; off < 16; off <<= 1) L += __shfl_xor(L, off);
      int p = p0 + w * 16 + lg * 4 + j;
      if (p < PP) {
        float inv = (L > 0.f) ? 1.0f / L : 0.f;
        #pragma unroll
        for (int dt = 0; dt < 4; ++dt)
          attn_out[((size_t)(b * PP + p)) * 512 + h * 64 + dt * 16 + lr] = f2bf(Oa[dt][j] * inv);
      }
    }
  }
}

// ---------------------------------------------------------------- K3: mh = attn_out @ mh_w^T + mh_b  (MFMA bf16, K-step 64, bf16 I/O)
__global__ __launch_bounds__(256) void k_mhgemm(
    const unsigned short* __restrict__ A, const float* __restrict__ W,
    const float* __restrict__ bias, unsigned short* __restrict__ out) {
  __shared__ unsigned short Xs[64][72];
  __shared__ unsigned short Ws[64][72];
  const int t = threadIdx.x;
  const int lane = t & 63;
  const int w = t >> 6;
  const int lr = lane & 15, lg = lane >> 4;
  const int rowBase = blockIdx.y * 64, colBase = blockIdx.x * 64;

  f32x4 acc[4];
  #pragma unroll
  for (int m = 0; m < 4; ++m) { acc[m][0] = 0.f; acc[m][1] = 0.f; acc[m][2] = 0.f; acc[m][3] = 0.f; }

  for (int kt = 0; kt < 8; ++kt) {
    const int koff = kt * 64;
    __syncthreads();
    // A: pure bf16 16B copies (64 rows x 8 ushort8 slots = 512 -> 2 iters)
    #pragma unroll
    for (int i = 0; i < 2; ++i) {
      int idx = i * 256 + t;
      int r = idx >> 3, c8 = (idx & 7) * 8;
      *(bf16x8*)&Xs[r][c8] =
          *(const bf16x8*)&A[(size_t)(rowBase + r) * 512 + koff + c8];
    }
    // W: fp32 -> bf16 convert staging (64 rows x 16 f4 slots = 1024 -> 4 iters)
    #pragma unroll
    for (int i = 0; i < 4; ++i) {
      int s = i * 256 + t;
      int r = s >> 4, c4 = (s & 15) * 4;
      F4 wv;
      wv.v = *(const float4*)&W[(size_t)(colBase + r) * 512 + koff + c4];
      unsigned short* wd = &Ws[r][c4];
      wd[0] = f2bf(wv.f[0]); wd[1] = f2bf(wv.f[1]); wd[2] = f2bf(wv.f[2]); wd[3] = f2bf(wv.f[3]);
    }
    __syncthreads();
    #pragma unroll
    for (int kb = 0; kb < 2; ++kb) {
      bf16x8 bfr = *(bf16x8*)&Ws[w * 16 + lr][kb * 32 + lg * 8];
      #pragma unroll
      for (int m = 0; m < 4; ++m) {
        bf16x8 af = *(bf16x8*)&Xs[m * 16 + lr][kb * 32 + lg * 8];
        acc[m] = __builtin_amdgcn_mfma_f32_16x16x32_bf16(af, bfr, acc[m], 0, 0, 0);
      }
    }
  }

  const int o = colBase + w * 16 + lr;
  const float bv = bias[o];
  #pragma unroll
  for (int m = 0; m < 4; ++m) {
    #pragma unroll
    for (int j = 0; j < 4; ++j) {
      int row = rowBase + m * 16 + lg * 4 + j;
      out[(size_t)row * 512 + o] = f2bf(acc[m][j] + bv);
    }
  }
}

// ---------------------------------------------------------------- K4a: score2 = mh @ shk (MFMA bf16, K-step 64) + tanh-clip epilogue
__global__ __launch_bounds__(256) void k_final_score(
    const unsigned short* __restrict__ mh, const float* __restrict__ shk,
    const float* __restrict__ cur_dist, const float* __restrict__ rmax,
    const float* __restrict__ mask, const float* __restrict__ dist_alpha,
    float* __restrict__ sc_out) {
  __shared__ unsigned short As[112][72];
  __shared__ unsigned short Bt[64][72];
  const int t = threadIdx.x;
  const int lane = t & 63;
  const int w = t >> 6;
  const int lr = lane & 15, lg = lane >> 4;
  const int n0 = blockIdx.x * 64, b = blockIdx.y;

  f32x4 acc[7];
  #pragma unroll
  for (int m = 0; m < 7; ++m) { acc[m][0] = 0.f; acc[m][1] = 0.f; acc[m][2] = 0.f; acc[m][3] = 0.f; }

  for (int kt = 0; kt < 8; ++kt) {
    const int k0 = kt * 64;
    __syncthreads();
    // A: bf16 16B copies (112 rows x 8 ushort8 slots = 896 -> 4 iters guarded)
    #pragma unroll
    for (int i = 0; i < 4; ++i) {
      int idx = i * 256 + t;
      if (idx < 896) {
        int r = idx >> 3, c8 = (idx & 7) * 8;
        bf16x8 v = bf8_zero();
        if (r < PP) v = *(const bf16x8*)&mh[(size_t)(b * PP + r) * 512 + k0 + c8];
        *(bf16x8*)&As[r][c8] = v;
      }
    }
    // B transposed: Bt[n - n0][k - k0], 64x64 from shk[b][k][n]
    {
      int a = t & 15, kb = t >> 4;
      F4 rowv[4];
      #pragma unroll
      for (int r = 0; r < 4; ++r) {
        int k = k0 + 4 * kb + r;
        int n = n0 + 4 * a;
        rowv[r].v = (n < NN) ? *(const float4*)&shk[((size_t)b * EE + k) * NN + n]
                             : make_float4(0.f, 0.f, 0.f, 0.f);
      }
      #pragma unroll
      for (int c = 0; c < 4; ++c) {
        unsigned short* dst = &Bt[4 * a + c][4 * kb];
        dst[0] = f2bf(rowv[0].f[c]); dst[1] = f2bf(rowv[1].f[c]);
        dst[2] = f2bf(rowv[2].f[c]); dst[3] = f2bf(rowv[3].f[c]);
      }
    }
    __syncthreads();
    #pragma unroll
    for (int kb = 0; kb < 2; ++kb) {
      bf16x8 bfr = *(bf16x8*)&Bt[w * 16 + lr][kb * 32 + lg * 8];
      #pragma unroll
      for (int m = 0; m < 7; ++m) {
        bf16x8 af = *(bf16x8*)&As[m * 16 + lr][kb * 32 + lg * 8];
        acc[m] = __builtin_amdgcn_mfma_f32_16x16x32_bf16(af, bfr, acc[m], 0, 0, 0);
      }
    }
  }

  const float alpha = dist_alpha[0];
  const int n = n0 + w * 16 + lr;
  if (n < NN) {
    #pragma unroll
    for (int m = 0; m < 7; ++m) {
      #pragma unroll
      for (int j = 0; j < 4; ++j) {
        int p = m * 16 + lg * 4 + j;
        if (p >= PP) continue;
        size_t rb = (size_t)(b * PP + p) * NN;
        float rmx = rmax[b * PP + p];
        float cd = cur_dist[rb + n];
        float mk = mask[rb + n];
        sc_out[rb + n] = CLIPV * fast_tanh(acc[m][j] * INVSQE - alpha * cd / rmx) + mk;
      }
    }
  }
}

// ---------------------------------------------------------------- K4b: row softmax over N — no-max (sc bounded +-10 or -1e30)
__global__ __launch_bounds__(256) void k_softmax(const float* __restrict__ sc,
                                                 float* __restrict__ out) {
  __shared__ float redsum[4];
  const int row = blockIdx.x;
  const int t = threadIdx.x;
  const float* src = sc + (size_t)row * NN;
  float e[4];
  float s = 0.f;
  #pragma unroll
  for (int i = 0; i < 4; ++i) {
    int n = i * 256 + t;
    e[i] = (n < NN) ? __expf(src[n]) : 0.f;
    s += e[i];
  }
  #pragma unroll
  for (int off = 32; off; off >>= 1) s += __shfl_xor(s, off);
  int wid = t >> 6, lane = t & 63;
  if (lane == 0) redsum[wid] = s;
  __syncthreads();
  s = redsum[0] + redsum[1] + redsum[2] + redsum[3];
  float inv = 1.0f / s;
  #pragma unroll
  for (int i = 0; i < 4; ++i) {
    int n = i * 256 + t;
    if (n < NN) out[(size_t)row * NN + n] = e[i] * inv;
  }
}

// ----------------------------------------------------------------
extern "C" void kernel_launch(void* const* d_in, const int* in_sizes, int n_in,
                              void* d_out, int out_size, void* d_ws, size_t ws_size,
                              hipStream_t stream) {
  const float* eln       = (const float*)d_in[0];
  const float* ela       = (const float*)d_in[1];
  const float* cur_dist  = (const float*)d_in[2];
  const float* ninf      = (const float*)d_in[3];
  const float* lengths   = (const float*)d_in[4];
  const float* max_dis   = (const float*)d_in[5];
  const float* remain    = (const float*)d_in[6];
  const float* q_first   = (const float*)d_in[7];
  const float* kten      = (const float*)d_in[8];
  const float* vten      = (const float*)d_in[9];
  const float* shk       = (const float*)d_in[10];
  const float* Wq        = (const float*)d_in[11];
  const float* dis_emb   = (const float*)d_in[12];
  const float* mh_w      = (const float*)d_in[13];
  const float* mh_b      = (const float*)d_in[14];
  const float* dalpha    = (const float*)d_in[15];
  const int*   depot     = (const int*)d_in[16];
  const int*   route_cnt = (const int*)d_in[17];
  const int*   left_city = (const int*)d_in[18];
  const int*   city_num  = (const int*)d_in[19];
  float* out = (float*)d_out;

  // Workspace: q/attn/mh intermediates are bf16 now (same float-offset layout
  // as before; bf16 regions just use the lower half of each slot).
  float* ws = (float*)d_ws;
  unsigned short* q_ws    = (unsigned short*)ws;                         // 6400*512 bf16
  unsigned short* attn_ws = (unsigned short*)(ws + (size_t)ROWS * 512);  // 6400*512 bf16
  unsigned short* mh_ws   = (unsigned short*)(ws + (size_t)2 * ROWS * 512); // 6400*512 bf16
  float* sc_ws   = ws + (size_t)3 * ROWS * 512;          // 6400*1000 fp32
  float* rmax_ws = sc_ws + (size_t)ROWS * NN;            // 6400

  k_rowmax<<<ROWS / 4, 256, 0, stream>>>(cur_dist, rmax_ws);
  k_qgemm<<<dim3(8, 100), 256, 0, stream>>>(eln, ela, lengths, max_dis, remain,
                                            q_first, Wq, dis_emb, depot, route_cnt,
                                            left_city, city_num, q_ws);
  k_attn<<<1024, 256, 0, stream>>>(q_ws, kten, vten, ninf, attn_ws);
  k_mhgemm<<<dim3(8, 100), 256, 0, stream>>>(attn_ws, mh_w, mh_b, mh_ws);
  k_final_score<<<dim3(16, 64), 256, 0, stream>>>(mh_ws, shk, cur_dist, rmax_ws,
                                                  ninf, dalpha, sc_ws);
  k_softmax<<<ROWS, 256, 0, stream>>>(sc_ws, out);
}